// Round 3
// baseline (819.536 us; speedup 1.0000x reference)
//
#include <hip/hip_runtime.h>

#define Bc 8
#define Nc 512
#define INc 64
#define Hc 128
#define Atc 32
#define REDc 32
#define OUTc 3
#define Lc 3

__device__ __forceinline__ float tanh_fast(float x) {
    // tanh(x) = 1 - 2/(e^{2x}+1); saturates correctly for |x| large.
    float e = __expf(2.f * x);
    return 1.f - 2.f * __builtin_amdgcn_rcpf(e + 1.f);
}

// Y[m,n] = act( sum_k (X[m,k]*sc[b,k]) * W[n,k] + b[n] )
// X: MxK row-major, W: NOUT x K row-major. 128 threads, G=128/NOUT groups over rows.
template <int TM, int NOUT>
__global__ __launch_bounds__(128) void gemm_tm(
        const float* __restrict__ X, const float* __restrict__ W,
        const float* __restrict__ bias, float* __restrict__ Y,
        int K, int act, const float* __restrict__ scale) {
    constexpr int G = 128 / NOUT;
    constexpr int RPG = TM / G;
    __shared__ float xs[TM * 128];
    int m0 = blockIdx.x * TM;
    int t = threadIdx.x;
    const float* sc = scale ? scale + (size_t)(m0 >> 9) * K : nullptr;
    // vectorized staging: TM*K floats, float4
    for (int idx4 = t; idx4 < TM * K / 4; idx4 += 128) {
        float4 v = ((const float4*)(X + (size_t)m0 * K))[idx4];
        if (sc) {
            int base = idx4 * 4;
            v.x *= sc[base % K]; v.y *= sc[(base + 1) % K];
            v.z *= sc[(base + 2) % K]; v.w *= sc[(base + 3) % K];
        }
        ((float4*)xs)[idx4] = v;
    }
    __syncthreads();
    int n = t % NOUT;
    int grp = t / NOUT;
    float bv = bias ? bias[n] : 0.f;
    float acc[RPG];
#pragma unroll
    for (int r = 0; r < RPG; ++r) acc[r] = bv;
    const float* w = W + (size_t)n * K;
    for (int k = 0; k < K; k += 4) {
        float4 wv = *(const float4*)(w + k);
#pragma unroll
        for (int r = 0; r < RPG; ++r) {
            float4 xv = *(const float4*)(xs + (grp * RPG + r) * K + k);
            acc[r] = fmaf(xv.x, wv.x, acc[r]);
            acc[r] = fmaf(xv.y, wv.y, acc[r]);
            acc[r] = fmaf(xv.z, wv.z, acc[r]);
            acc[r] = fmaf(xv.w, wv.w, acc[r]);
        }
    }
#pragma unroll
    for (int r = 0; r < RPG; ++r) {
        float v = acc[r];
        if (act) v = fmaxf(v, 0.f);
        Y[(size_t)(m0 + grp * RPG + r) * NOUT + n] = v;
    }
}

// T[b,i,h] = (1+eps)*X[b,i,h] + sum_j A[b,i,j]*X[b,j,h].  A binary: compact nonzeros first.
__global__ __launch_bounds__(128) void spmm_eps(const float* __restrict__ A, const float* __restrict__ X,
                         const float* __restrict__ eps_ptr, float* __restrict__ T) {
    int bi = blockIdx.x;          // b*Nc + i
    int b = bi >> 9;
    int h = threadIdx.x;          // 128
    __shared__ int idxs[Nc];
    __shared__ int cnt;
    if (h == 0) cnt = 0;
    __syncthreads();
    const float4* Ar4 = (const float4*)(A + (size_t)bi * Nc);
    float4 a4 = Ar4[h];           // j = 4h..4h+3
    if (a4.x != 0.f) idxs[atomicAdd(&cnt, 1)] = 4 * h + 0;
    if (a4.y != 0.f) idxs[atomicAdd(&cnt, 1)] = 4 * h + 1;
    if (a4.z != 0.f) idxs[atomicAdd(&cnt, 1)] = 4 * h + 2;
    if (a4.w != 0.f) idxs[atomicAdd(&cnt, 1)] = 4 * h + 3;
    __syncthreads();
    int n = cnt;
    const float* Xb = X + (size_t)b * Nc * Hc;
    float acc = 0.f;
    for (int q = 0; q < n; ++q) {
        int j = idxs[q];
        acc += Xb[(size_t)j * Hc + h];
    }
    float eps = eps_ptr[0];
    size_t o = (size_t)bi * Hc + h;
    T[o] = (1.f + eps) * X[o] + acc;
}

__global__ void topo_combine(const float* __restrict__ Xh, const float* __restrict__ hA,
                             const float* __restrict__ hAC, const float* __restrict__ theta,
                             float* __restrict__ Xp) {
    int idx = blockIdx.x * blockDim.x + threadIdx.x;
    if (idx >= Bc * Nc * Hc) return;
    int h = idx & (Hc - 1);
    Xp[idx] = Xh[idx] + tanh_fast(hA[idx] * theta[2 * h]) + tanh_fast(hAC[idx] * theta[2 * h + 1]);
}

// Fully fused attention: scores -> softmax -> ctx -> alpha@Xy -> epilogue.
// grid = B*(N/4) blocks, 256 threads; 4 query rows per block.
__global__ __launch_bounds__(256) void attn_all(
        const float* __restrict__ ho, const float* __restrict__ h1,
        const float* __restrict__ wphi, const float* __restrict__ Xy,
        const float* __restrict__ we_w, const float* __restrict__ we_b,
        const float* __restrict__ XA, const float* __restrict__ XAC,
        float* __restrict__ Xbar) {
    int blk = blockIdx.x;
    int b = blk >> 7;
    int i0 = (blk & 127) * 4;
    int t = threadIdx.x;
    __shared__ float als[4 * Nc];       // scores, then normalized alpha (8 KB)
    __shared__ float hos[4 * 32];
    __shared__ float part[8 * 4 * 32];  // ctx partials per j-group (4 KB)
    __shared__ float ctxs[4 * 32];
    if (t < 128) hos[t] = ho[((size_t)b * Nc + i0) * 32 + t];
    float wpr[32];
    {
        const float4* wp4 = (const float4*)wphi;
#pragma unroll
        for (int q = 0; q < 8; ++q) {
            float4 v = wp4[q];
            wpr[4 * q] = v.x; wpr[4 * q + 1] = v.y; wpr[4 * q + 2] = v.z; wpr[4 * q + 3] = v.w;
        }
    }
    __syncthreads();
    const float* h1b = h1 + (size_t)b * Nc * 32;
    // ---- Phase 1: scores into als ----
#pragma unroll
    for (int jj = 0; jj < 2; ++jj) {
        int j = t + jj * 256;
        const float4* h1j = (const float4*)(h1b + (size_t)j * 32);
        float4 h1r[8];
#pragma unroll
        for (int q = 0; q < 8; ++q) h1r[q] = h1j[q];
#pragma unroll
        for (int i = 0; i < 4; ++i) {
            const float4* hp = (const float4*)(hos + i * 32);
            float acc = 0.f;
#pragma unroll
            for (int q = 0; q < 8; ++q) {
                float4 hv = hp[q];
                acc = fmaf(tanh_fast(hv.x + h1r[q].x), wpr[4 * q], acc);
                acc = fmaf(tanh_fast(hv.y + h1r[q].y), wpr[4 * q + 1], acc);
                acc = fmaf(tanh_fast(hv.z + h1r[q].z), wpr[4 * q + 2], acc);
                acc = fmaf(tanh_fast(hv.w + h1r[q].w), wpr[4 * q + 3], acc);
            }
            als[i * Nc + j] = acc;
        }
    }
    __syncthreads();
    // ---- Phase 2: softmax per row (one wave per row) ----
    {
        int r = t >> 6, lane = t & 63;
        float* row = als + r * Nc;
        float v[8];
        float m = -1e30f;
#pragma unroll
        for (int q = 0; q < 8; ++q) { v[q] = row[lane + q * 64]; m = fmaxf(m, v[q]); }
#pragma unroll
        for (int o = 32; o > 0; o >>= 1) m = fmaxf(m, __shfl_xor(m, o));
        float sum = 0.f;
#pragma unroll
        for (int q = 0; q < 8; ++q) { v[q] = __expf(v[q] - m); sum += v[q]; }
#pragma unroll
        for (int o = 32; o > 0; o >>= 1) sum += __shfl_xor(sum, o);
        float rinv = 1.f / sum;
#pragma unroll
        for (int q = 0; q < 8; ++q) row[lane + q * 64] = v[q] * rinv;
    }
    __syncthreads();
    // ---- Phase 3: ctx[i,k] = sum_j alpha[i,j]*tanh(ho[i,k]+h1[j,k]) ----
    {
        int k = t & 31, jg = t >> 5;
        float hok[4], pa[4];
#pragma unroll
        for (int i = 0; i < 4; ++i) { hok[i] = hos[i * 32 + k]; pa[i] = 0.f; }
        for (int jq = 0; jq < 64; ++jq) {
            int j = jg * 64 + jq;
            float h1v = h1b[(size_t)j * 32 + k];
#pragma unroll
            for (int i = 0; i < 4; ++i)
                pa[i] = fmaf(als[i * Nc + j], tanh_fast(hok[i] + h1v), pa[i]);
        }
#pragma unroll
        for (int i = 0; i < 4; ++i) part[(jg * 4 + i) * 32 + k] = pa[i];
    }
    __syncthreads();
    if (t < 128) {
        int i = t >> 5, k = t & 31;
        float c = 0.f;
#pragma unroll
        for (int jg = 0; jg < 8; ++jg) c += part[(jg * 4 + i) * 32 + k];
        ctxs[i * 32 + k] = c;
    }
    __syncthreads();
    // ---- Phase 4: alpha@Xy + We·ctx + we_b + XA + XAC ----
    {
        int i_loc = t >> 6;
        int h2 = (t & 63) * 2;
        const float* Xyb = Xy + (size_t)b * Nc * Hc;
        const float* al = als + i_loc * Nc;
        float ax = 0.f, ay = 0.f;
        for (int j = 0; j < Nc; j += 4) {
#pragma unroll
            for (int u = 0; u < 4; ++u) {
                float av = al[j + u];
                float2 x = *(const float2*)(Xyb + (size_t)(j + u) * Hc + h2);
                ax = fmaf(av, x.x, ax);
                ay = fmaf(av, x.y, ay);
            }
        }
        float s0 = 0.f, s1 = 0.f;
        const float* c = ctxs + i_loc * 32;
        const float* w0 = we_w + (size_t)h2 * 32;
        const float* w1p = we_w + (size_t)(h2 + 1) * 32;
#pragma unroll
        for (int q = 0; q < 32; ++q) {
            float cv = c[q];
            s0 = fmaf(w0[q], cv, s0);
            s1 = fmaf(w1p[q], cv, s1);
        }
        size_t o = ((size_t)b * Nc + i0 + i_loc) * Hc + h2;
        float2 wb = *(const float2*)(we_b + h2);
        float2 g1 = *(const float2*)(XA + o);
        float2 g2 = *(const float2*)(XAC + o);
        float2 outv;
        outv.x = ax + s0 + wb.x + g1.x + g2.x;
        outv.y = ay + s1 + wb.y + g1.y + g2.y;
        *(float2*)(Xbar + o) = outv;
    }
}

// partial row-sum for SE: grid B*8, 128 threads
__global__ __launch_bounds__(128) void rowsum_partial(const float* __restrict__ Xbar, float* __restrict__ P) {
    int blk = blockIdx.x;
    int b = blk >> 3, p = blk & 7;
    int t = threadIdx.x;
    const float* Xb = Xbar + ((size_t)b * Nc + p * 64) * Hc;
    float acc = 0.f;
    for (int i = 0; i < 64; ++i) acc += Xb[(size_t)i * Hc + t];
    P[(size_t)blk * Hc + t] = acc;
}

// grid = B, 128 threads: y2[b,h] = sigmoid(lin2(relu(lin1(sum_i Xbar))))
__global__ __launch_bounds__(128) void se_kernel(const float* __restrict__ P, const float* __restrict__ l1w,
                          const float* __restrict__ l1b, const float* __restrict__ l2w,
                          const float* __restrict__ l2b, float* __restrict__ y2) {
    int b = blockIdx.x;
    int t = threadIdx.x; // 128
    __shared__ float s[Hc];
    __shared__ float y1s[REDc];
    float acc = 0.f;
#pragma unroll
    for (int p = 0; p < 8; ++p) acc += P[((size_t)b * 8 + p) * Hc + t];
    s[t] = acc;
    __syncthreads();
    if (t < REDc) {
        float a = l1b[t];
        const float* w = l1w + (size_t)t * Hc;
        for (int k = 0; k < Hc; ++k) a = fmaf(s[k], w[k], a);
        y1s[t] = fmaxf(a, 0.f);
    }
    __syncthreads();
    float a = l2b[t];
    const float* w2 = l2w + (size_t)t * REDc;
#pragma unroll
    for (int k = 0; k < REDc; ++k) a = fmaf(y1s[k], w2[k], a);
    y2[(size_t)b * Hc + t] = 1.f / (1.f + __expf(-a));
}

// grid = B*N, 64 threads: head1(relu) + head2 fused
__global__ __launch_bounds__(64) void head_kernel(const float* __restrict__ Xp, const float* __restrict__ h1w,
                            const float* __restrict__ h1b, const float* __restrict__ h2w,
                            const float* __restrict__ h2b, float* __restrict__ out) {
    int m = blockIdx.x;
    int t = threadIdx.x; // 64
    __shared__ float xs[Hc];
    __shared__ float hs[64];
    xs[t] = Xp[(size_t)m * Hc + t];
    xs[t + 64] = Xp[(size_t)m * Hc + t + 64];
    __syncthreads();
    float a = h1b[t];
    const float* w = h1w + (size_t)t * Hc;
    for (int k = 0; k < Hc; ++k) a = fmaf(xs[k], w[k], a);
    hs[t] = fmaxf(a, 0.f);
    __syncthreads();
    if (t < OUTc) {
        float o = h2b[t];
        const float* w2 = h2w + (size_t)t * 64;
#pragma unroll
        for (int k = 0; k < 64; ++k) o = fmaf(hs[k], w2[k], o);
        out[(size_t)m * OUTc + t] = o;
    }
}

extern "C" void kernel_launch(void* const* d_in, const int* in_sizes, int n_in,
                              void* d_out, int out_size, void* d_ws, size_t ws_size,
                              hipStream_t stream) {
    const float* X       = (const float*)d_in[0];
    const float* A       = (const float*)d_in[1];
    const float* Acg     = (const float*)d_in[2];
    const float* embed_w = (const float*)d_in[3];
    const float* embed_b = (const float*)d_in[4];
    const float* topo_eps= (const float*)d_in[5];
    const float* topo_w  = (const float*)d_in[6];
    const float* topo_b  = (const float*)d_in[7];
    const float* theta   = (const float*)d_in[8];
    const float* gin_eps = (const float*)d_in[9];
    const float* gin_w   = (const float*)d_in[10];
    const float* gin_b   = (const float*)d_in[11];
    const float* wo      = (const float*)d_in[12];
    const float* w1      = (const float*)d_in[13];
    const float* wphi    = (const float*)d_in[14];
    const float* wy_w    = (const float*)d_in[15];
    const float* wy_b    = (const float*)d_in[16];
    const float* we_w    = (const float*)d_in[17];
    const float* we_b    = (const float*)d_in[18];
    const float* lin1_w  = (const float*)d_in[19];
    const float* lin1_b  = (const float*)d_in[20];
    const float* lin2_w  = (const float*)d_in[21];
    const float* lin2_b  = (const float*)d_in[22];
    const float* mlp_w   = (const float*)d_in[23];
    const float* mlp_b   = (const float*)d_in[24];
    const float* head1_w = (const float*)d_in[25];
    const float* head1_b = (const float*)d_in[26];
    const float* head2_w = (const float*)d_in[27];
    const float* head2_b = (const float*)d_in[28];
    float* out = (float*)d_out;

    float* ws = (float*)d_ws;
    const int MN = Bc * Nc;              // 4096
    const size_t SZ = (size_t)MN * Hc;   // 524288
    float* Xh   = ws;
    float* Xp   = Xh + SZ;
    float* T    = Xp + SZ;
    float* G1   = T + SZ;
    float* G2   = G1 + SZ;
    float* Xy   = G2 + SZ;
    float* Xbar = Xy + SZ;
    float* hov  = Xbar + SZ;             // MN*32
    float* h1v  = hov + (size_t)MN * Atc;
    float* y2   = h1v + (size_t)MN * Atc;  // B*H
    float* P    = y2 + (size_t)Bc * Hc;    // B*8*H

    // embed: Xh = X @ embed_w.T + b
    gemm_tm<8, 128><<<MN / 8, 128, 0, stream>>>(X, embed_w, embed_b, Xh, INc, 0, nullptr);
    // topo GIN on A and Ac
    spmm_eps<<<MN, 128, 0, stream>>>(A, Xh, topo_eps, T);
    gemm_tm<8, 128><<<MN / 8, 128, 0, stream>>>(T, topo_w, topo_b, G1, Hc, 1, nullptr);
    spmm_eps<<<MN, 128, 0, stream>>>(Acg, Xh, topo_eps, T);
    gemm_tm<8, 128><<<MN / 8, 128, 0, stream>>>(T, topo_w, topo_b, G2, Hc, 1, nullptr);
    topo_combine<<<(MN * Hc + 255) / 256, 256, 0, stream>>>(Xh, G1, G2, theta, Xp);

    for (int l = 0; l < Lc; ++l) {
        spmm_eps<<<MN, 128, 0, stream>>>(A, Xp, gin_eps + l * 2 + 0, T);
        gemm_tm<8, 128><<<MN / 8, 128, 0, stream>>>(T, gin_w + (size_t)(l * 2 + 0) * Hc * Hc,
                                                    gin_b + (size_t)(l * 2 + 0) * Hc, G1, Hc, 1, nullptr);
        spmm_eps<<<MN, 128, 0, stream>>>(Acg, Xp, gin_eps + l * 2 + 1, T);
        gemm_tm<8, 128><<<MN / 8, 128, 0, stream>>>(T, gin_w + (size_t)(l * 2 + 1) * Hc * Hc,
                                                    gin_b + (size_t)(l * 2 + 1) * Hc, G2, Hc, 1, nullptr);
        gemm_tm<8, 32><<<MN / 8, 128, 0, stream>>>(Xp, wo + (size_t)l * Atc * Hc, nullptr, hov, Hc, 0, nullptr);
        gemm_tm<8, 32><<<MN / 8, 128, 0, stream>>>(Xp, w1 + (size_t)l * Atc * Hc, nullptr, h1v, Hc, 0, nullptr);
        gemm_tm<8, 128><<<MN / 8, 128, 0, stream>>>(Xp, wy_w + (size_t)l * Hc * Hc, wy_b + (size_t)l * Hc, Xy, Hc, 0, nullptr);
        attn_all<<<MN / 4, 256, 0, stream>>>(hov, h1v, wphi + (size_t)l * Atc, Xy,
                                             we_w + (size_t)l * Hc * Atc, we_b + (size_t)l * Hc,
                                             G1, G2, Xbar);
        rowsum_partial<<<Bc * 8, 128, 0, stream>>>(Xbar, P);
        se_kernel<<<Bc, 128, 0, stream>>>(P, lin1_w + (size_t)l * REDc * Hc, lin1_b + (size_t)l * REDc,
                                          lin2_w + (size_t)l * Hc * REDc, lin2_b + (size_t)l * Hc, y2);
        gemm_tm<8, 128><<<MN / 8, 128, 0, stream>>>(Xbar, mlp_w + (size_t)l * Hc * Hc, mlp_b + (size_t)l * Hc, Xp, Hc, 0, y2);
    }
    head_kernel<<<MN, 64, 0, stream>>>(Xp, head1_w, head1_b, head2_w, head2_b, out);
}

// Round 4
// 560.205 us; speedup vs baseline: 1.4629x; 1.4629x over previous
//
#include <hip/hip_runtime.h>

#define Bc 8
#define Nc 512
#define INc 64
#define Hc 128
#define Atc 32
#define REDc 32
#define OUTc 3
#define Lc 3

__device__ __forceinline__ float tanh_fast(float x) {
    float e = __expf(2.f * x);
    return 1.f - 2.f * __builtin_amdgcn_rcpf(e + 1.f);
}

// Generic small GEMM: Y[m,n] = act( sum_k (X[m,k]*sc[b,k]) * W[n,k] + b[n] )
// 256 threads, TM rows/block, NOUT=128. K is compile-time pow2.
template <int TM, int K, int ACT>
__global__ __launch_bounds__(256) void gemm256(
        const float* __restrict__ X, const float* __restrict__ W,
        const float* __restrict__ bias, float* __restrict__ Y,
        const float* __restrict__ scale) {
    constexpr int RPG = TM / 2;           // grp = t>>7 in {0,1}
    __shared__ float xs[TM * K];
    int m0 = blockIdx.x * TM;
    int t = threadIdx.x;
    const float* sc = scale ? scale + (size_t)(m0 >> 9) * K : nullptr;
    for (int idx4 = t; idx4 < TM * K / 4; idx4 += 256) {
        float4 v = ((const float4*)(X + (size_t)m0 * K))[idx4];
        if (sc) {
            int base = idx4 * 4;
            v.x *= sc[base & (K - 1)]; v.y *= sc[(base + 1) & (K - 1)];
            v.z *= sc[(base + 2) & (K - 1)]; v.w *= sc[(base + 3) & (K - 1)];
        }
        ((float4*)xs)[idx4] = v;
    }
    __syncthreads();
    int n = t & 127;
    int grp = t >> 7;
    float bv = bias ? bias[n] : 0.f;
    float acc[RPG];
#pragma unroll
    for (int r = 0; r < RPG; ++r) acc[r] = bv;
    const float* w = W + (size_t)n * K;
    for (int k = 0; k < K; k += 4) {
        float4 wv = *(const float4*)(w + k);
#pragma unroll
        for (int r = 0; r < RPG; ++r) {
            float4 xv = *(const float4*)(xs + (grp * RPG + r) * K + k);
            acc[r] = fmaf(xv.x, wv.x, acc[r]); acc[r] = fmaf(xv.y, wv.y, acc[r]);
            acc[r] = fmaf(xv.z, wv.z, acc[r]); acc[r] = fmaf(xv.w, wv.w, acc[r]);
        }
    }
#pragma unroll
    for (int r = 0; r < RPG; ++r) {
        float v = acc[r];
        if (ACT) v = fmaxf(v, 0.f);
        Y[(size_t)(m0 + grp * RPG + r) * 128 + n] = v;
    }
}

// Dual SpMM: T1 = (1+eA)X + A@X ; T2 = (1+eC)X + Ac@X. One block per row.
__global__ __launch_bounds__(128) void spmm2(
        const float* __restrict__ A, const float* __restrict__ Acg,
        const float* __restrict__ X, const float* __restrict__ eA,
        const float* __restrict__ eC, float* __restrict__ T1, float* __restrict__ T2) {
    int bi = blockIdx.x;
    int b = bi >> 9;
    int h = threadIdx.x;
    __shared__ int idxA[Nc], idxC[Nc];
    __shared__ int cntA, cntC;
    if (h == 0) { cntA = 0; cntC = 0; }
    __syncthreads();
    {
        float4 a4 = ((const float4*)(A + (size_t)bi * Nc))[h];
        if (a4.x != 0.f) idxA[atomicAdd(&cntA, 1)] = 4 * h;
        if (a4.y != 0.f) idxA[atomicAdd(&cntA, 1)] = 4 * h + 1;
        if (a4.z != 0.f) idxA[atomicAdd(&cntA, 1)] = 4 * h + 2;
        if (a4.w != 0.f) idxA[atomicAdd(&cntA, 1)] = 4 * h + 3;
        float4 c4 = ((const float4*)(Acg + (size_t)bi * Nc))[h];
        if (c4.x != 0.f) idxC[atomicAdd(&cntC, 1)] = 4 * h;
        if (c4.y != 0.f) idxC[atomicAdd(&cntC, 1)] = 4 * h + 1;
        if (c4.z != 0.f) idxC[atomicAdd(&cntC, 1)] = 4 * h + 2;
        if (c4.w != 0.f) idxC[atomicAdd(&cntC, 1)] = 4 * h + 3;
    }
    __syncthreads();
    int nA = cntA, nC = cntC;
    const float* Xb = X + (size_t)b * Nc * Hc;
    float a1 = 0.f, a2 = 0.f;
    for (int q = 0; q < nA; ++q) a1 += Xb[(size_t)idxA[q] * Hc + h];
    for (int q = 0; q < nC; ++q) a2 += Xb[(size_t)idxC[q] * Hc + h];
    size_t o = (size_t)bi * Hc + h;
    float xv = X[o];
    T1[o] = (1.f + eA[0]) * xv + a1;
    T2[o] = (1.f + eC[0]) * xv + a2;
}

// Topo dual GIN + combine: Xp = Xh + tanh(relu(T1·Wt+b)*th0) + tanh(relu(T2·Wt+b)*th1)
__global__ __launch_bounds__(256) void gemm2_topo(
        const float* __restrict__ T1, const float* __restrict__ T2,
        const float* __restrict__ W, const float* __restrict__ bias,
        const float* __restrict__ Xh, const float* __restrict__ theta,
        float* __restrict__ Xp) {
    __shared__ float xs1[8 * Hc], xs2[8 * Hc];
    int m0 = blockIdx.x * 8;
    int t = threadIdx.x;
    for (int idx4 = t; idx4 < 8 * Hc / 4; idx4 += 256) {
        ((float4*)xs1)[idx4] = ((const float4*)(T1 + (size_t)m0 * Hc))[idx4];
        ((float4*)xs2)[idx4] = ((const float4*)(T2 + (size_t)m0 * Hc))[idx4];
    }
    __syncthreads();
    int n = t & 127, grp = t >> 7;
    float bv = bias[n];
    float ac1[4], ac2[4];
#pragma unroll
    for (int r = 0; r < 4; ++r) { ac1[r] = bv; ac2[r] = bv; }
    const float* w = W + (size_t)n * Hc;
    for (int k = 0; k < Hc; k += 4) {
        float4 wv = *(const float4*)(w + k);
#pragma unroll
        for (int r = 0; r < 4; ++r) {
            float4 x1 = *(const float4*)(xs1 + (grp * 4 + r) * Hc + k);
            float4 x2 = *(const float4*)(xs2 + (grp * 4 + r) * Hc + k);
            ac1[r] = fmaf(x1.x, wv.x, ac1[r]); ac1[r] = fmaf(x1.y, wv.y, ac1[r]);
            ac1[r] = fmaf(x1.z, wv.z, ac1[r]); ac1[r] = fmaf(x1.w, wv.w, ac1[r]);
            ac2[r] = fmaf(x2.x, wv.x, ac2[r]); ac2[r] = fmaf(x2.y, wv.y, ac2[r]);
            ac2[r] = fmaf(x2.z, wv.z, ac2[r]); ac2[r] = fmaf(x2.w, wv.w, ac2[r]);
        }
    }
    float th0 = theta[2 * n], th1 = theta[2 * n + 1];
#pragma unroll
    for (int r = 0; r < 4; ++r) {
        size_t o = (size_t)(m0 + grp * 4 + r) * Hc + n;
        float g1 = fmaxf(ac1[r], 0.f), g2 = fmaxf(ac2[r], 0.f);
        Xp[o] = Xh[o] + tanh_fast(g1 * th0) + tanh_fast(g2 * th1);
    }
}

// Layer dual GIN: GS = relu(T1·W1+b1) + relu(T2·W2+b2)
__global__ __launch_bounds__(256) void gemm2_gin(
        const float* __restrict__ T1, const float* __restrict__ T2,
        const float* __restrict__ W1, const float* __restrict__ b1,
        const float* __restrict__ W2, const float* __restrict__ b2,
        float* __restrict__ GS) {
    __shared__ float xs1[8 * Hc], xs2[8 * Hc];
    int m0 = blockIdx.x * 8;
    int t = threadIdx.x;
    for (int idx4 = t; idx4 < 8 * Hc / 4; idx4 += 256) {
        ((float4*)xs1)[idx4] = ((const float4*)(T1 + (size_t)m0 * Hc))[idx4];
        ((float4*)xs2)[idx4] = ((const float4*)(T2 + (size_t)m0 * Hc))[idx4];
    }
    __syncthreads();
    int n = t & 127, grp = t >> 7;
    float ac1[4], ac2[4];
    float bv1 = b1[n], bv2 = b2[n];
#pragma unroll
    for (int r = 0; r < 4; ++r) { ac1[r] = bv1; ac2[r] = bv2; }
    const float* w1 = W1 + (size_t)n * Hc;
    const float* w2 = W2 + (size_t)n * Hc;
    for (int k = 0; k < Hc; k += 4) {
        float4 wv1 = *(const float4*)(w1 + k);
        float4 wv2 = *(const float4*)(w2 + k);
#pragma unroll
        for (int r = 0; r < 4; ++r) {
            float4 x1 = *(const float4*)(xs1 + (grp * 4 + r) * Hc + k);
            float4 x2 = *(const float4*)(xs2 + (grp * 4 + r) * Hc + k);
            ac1[r] = fmaf(x1.x, wv1.x, ac1[r]); ac1[r] = fmaf(x1.y, wv1.y, ac1[r]);
            ac1[r] = fmaf(x1.z, wv1.z, ac1[r]); ac1[r] = fmaf(x1.w, wv1.w, ac1[r]);
            ac2[r] = fmaf(x2.x, wv2.x, ac2[r]); ac2[r] = fmaf(x2.y, wv2.y, ac2[r]);
            ac2[r] = fmaf(x2.z, wv2.z, ac2[r]); ac2[r] = fmaf(x2.w, wv2.w, ac2[r]);
        }
    }
#pragma unroll
    for (int r = 0; r < 4; ++r) {
        size_t o = (size_t)(m0 + grp * 4 + r) * Hc + n;
        GS[o] = fmaxf(ac1[r], 0.f) + fmaxf(ac2[r], 0.f);
    }
}

// Fused Xy / ho / h1 projections from Xp. 8 rows/block, 256 threads.
__global__ __launch_bounds__(256) void qkv_gemm(
        const float* __restrict__ Xp, const float* __restrict__ wy_w,
        const float* __restrict__ wy_b, const float* __restrict__ wo,
        const float* __restrict__ w1, float* __restrict__ Xy,
        float* __restrict__ hov, float* __restrict__ h1v) {
    __shared__ float xs[8 * Hc];
    int m0 = blockIdx.x * 8;
    int t = threadIdx.x;
    for (int idx4 = t; idx4 < 8 * Hc / 4; idx4 += 256)
        ((float4*)xs)[idx4] = ((const float4*)(Xp + (size_t)m0 * Hc))[idx4];
    __syncthreads();
    // Phase A: Xy (n in 0..127, 2 groups x 4 rows)
    {
        int n = t & 127, grp = t >> 7;
        float bv = wy_b[n];
        float acc[4];
#pragma unroll
        for (int r = 0; r < 4; ++r) acc[r] = bv;
        const float* w = wy_w + (size_t)n * Hc;
        for (int k = 0; k < Hc; k += 4) {
            float4 wv = *(const float4*)(w + k);
#pragma unroll
            for (int r = 0; r < 4; ++r) {
                float4 xv = *(const float4*)(xs + (grp * 4 + r) * Hc + k);
                acc[r] = fmaf(xv.x, wv.x, acc[r]); acc[r] = fmaf(xv.y, wv.y, acc[r]);
                acc[r] = fmaf(xv.z, wv.z, acc[r]); acc[r] = fmaf(xv.w, wv.w, acc[r]);
            }
        }
#pragma unroll
        for (int r = 0; r < 4; ++r)
            Xy[(size_t)(m0 + grp * 4 + r) * Hc + n] = acc[r];
    }
    // Phase B: ho / h1 (n2 in 0..63 -> wo or w1; 4 groups x 2 rows)
    {
        int n2 = t & 63, g2 = t >> 6;
        const float* w = (n2 < 32) ? (wo + (size_t)n2 * Hc) : (w1 + (size_t)(n2 - 32) * Hc);
        float acc[2] = {0.f, 0.f};
        for (int k = 0; k < Hc; k += 4) {
            float4 wv = *(const float4*)(w + k);
#pragma unroll
            for (int r = 0; r < 2; ++r) {
                float4 xv = *(const float4*)(xs + (g2 * 2 + r) * Hc + k);
                acc[r] = fmaf(xv.x, wv.x, acc[r]); acc[r] = fmaf(xv.y, wv.y, acc[r]);
                acc[r] = fmaf(xv.z, wv.z, acc[r]); acc[r] = fmaf(xv.w, wv.w, acc[r]);
            }
        }
#pragma unroll
        for (int r = 0; r < 2; ++r) {
            int m = m0 + g2 * 2 + r;
            if (n2 < 32) hov[(size_t)m * Atc + n2] = acc[r];
            else h1v[(size_t)m * Atc + (n2 - 32)] = acc[r];
        }
    }
}

// Scores + in-block softmax -> normalized alpha. 8 query rows per block, 256 threads.
__global__ __launch_bounds__(256) void score_sm(
        const float* __restrict__ ho, const float* __restrict__ h1,
        const float* __restrict__ wphi, float* __restrict__ Sout) {
    int blk = blockIdx.x;
    int b = blk >> 6;
    int i0 = (blk & 63) * 8;
    int t = threadIdx.x;
    __shared__ float als[8 * Nc];   // 16 KB
    __shared__ float hos[8 * 32];
    hos[t] = ho[((size_t)b * Nc + i0) * 32 + t];
    float wpr[32];
    {
        const float4* wp4 = (const float4*)wphi;
#pragma unroll
        for (int q = 0; q < 8; ++q) {
            float4 v = wp4[q];
            wpr[4 * q] = v.x; wpr[4 * q + 1] = v.y; wpr[4 * q + 2] = v.z; wpr[4 * q + 3] = v.w;
        }
    }
    __syncthreads();
    const float* h1b = h1 + (size_t)b * Nc * 32;
#pragma unroll
    for (int jj = 0; jj < 2; ++jj) {
        int j = t + jj * 256;
        const float4* h1j = (const float4*)(h1b + (size_t)j * 32);
        float4 h1r[8];
#pragma unroll
        for (int q = 0; q < 8; ++q) h1r[q] = h1j[q];
#pragma unroll
        for (int i = 0; i < 8; ++i) {
            const float4* hp = (const float4*)(hos + i * 32);
            float acc = 0.f;
#pragma unroll
            for (int q = 0; q < 8; ++q) {
                float4 hv = hp[q];
                acc = fmaf(tanh_fast(hv.x + h1r[q].x), wpr[4 * q], acc);
                acc = fmaf(tanh_fast(hv.y + h1r[q].y), wpr[4 * q + 1], acc);
                acc = fmaf(tanh_fast(hv.z + h1r[q].z), wpr[4 * q + 2], acc);
                acc = fmaf(tanh_fast(hv.w + h1r[q].w), wpr[4 * q + 3], acc);
            }
            als[i * Nc + j] = acc;
        }
    }
    __syncthreads();
    // softmax: 4 waves x 2 rows each, write normalized alpha to global
    int wv_ = t >> 6, lane = t & 63;
#pragma unroll
    for (int rr = 0; rr < 2; ++rr) {
        int r = wv_ + rr * 4;
        float* row = als + r * Nc;
        float v[8];
        float m = -1e30f;
#pragma unroll
        for (int q = 0; q < 8; ++q) { v[q] = row[lane + q * 64]; m = fmaxf(m, v[q]); }
#pragma unroll
        for (int o = 32; o > 0; o >>= 1) m = fmaxf(m, __shfl_xor(m, o));
        float sum = 0.f;
#pragma unroll
        for (int q = 0; q < 8; ++q) { v[q] = __expf(v[q] - m); sum += v[q]; }
#pragma unroll
        for (int o = 32; o > 0; o >>= 1) sum += __shfl_xor(sum, o);
        float rinv = 1.f / sum;
        float* Srow = Sout + ((size_t)b * Nc + i0 + r) * Nc;
#pragma unroll
        for (int q = 0; q < 8; ++q) Srow[lane + q * 64] = v[q] * rinv;
    }
}

// ctx[bi,k] = sum_j alpha[bi,j] * tanh(ho[bi,k] + h1[b,j,k]).  One block per row.
__global__ __launch_bounds__(256) void ctx_kernel(
        const float* __restrict__ alpha, const float* __restrict__ ho,
        const float* __restrict__ h1, float* __restrict__ ctxv) {
    int bi = blockIdx.x;
    int b = bi >> 9;
    int t = threadIdx.x;
    __shared__ float als[Nc];
    __shared__ float part[256];
    if (t < 128) ((float4*)als)[t] = ((const float4*)(alpha + (size_t)bi * Nc))[t];
    __syncthreads();
    int k = t & 31, jg = t >> 5;
    float hok = ho[(size_t)bi * 32 + k];
    const float* h1b = h1 + (size_t)b * Nc * 32;
    float acc = 0.f;
    for (int jq = 0; jq < 64; ++jq) {
        int j = jg * 64 + jq;
        acc = fmaf(als[j], tanh_fast(hok + h1b[(size_t)j * 32 + k]), acc);
    }
    part[t] = acc;
    __syncthreads();
    if (t < 32) {
        float c = 0.f;
#pragma unroll
        for (int g = 0; g < 8; ++g) c += part[g * 32 + t];
        ctxv[(size_t)bi * 32 + t] = c;
    }
}

// Xbar = alpha@Xy + We·ctx + we_b + GS.  8 rows/block, 256 threads.
// Main loop: thread = (jg = t>>5, h4 = t&31) owns acc4[8 rows] over its j-slice.
__global__ __launch_bounds__(256) void attn_out2(
        const float* __restrict__ alpha, const float* __restrict__ Xy,
        const float* __restrict__ ctxv, const float* __restrict__ we_w,
        const float* __restrict__ we_b, const float* __restrict__ GS,
        float* __restrict__ Xbar) {
    int blk = blockIdx.x;
    int b = blk >> 6;
    int i0 = (blk & 63) * 8;
    int t = threadIdx.x;
    __shared__ float als[8 * Nc];      // 16 KB
    __shared__ float4 part4[8 * 256];  // 32 KB  [jg][i][h4]
    __shared__ float ctxs[8 * 32];
    {
        const float4* ap = (const float4*)(alpha + ((size_t)b * Nc + i0) * Nc);
#pragma unroll
        for (int q = 0; q < 4; ++q) ((float4*)als)[t + q * 256] = ap[t + q * 256];
        ctxs[t] = ctxv[((size_t)b * Nc + i0) * 32 + t];
    }
    __syncthreads();
    int h4 = t & 31, jg = t >> 5;
    const float* Xyb = Xy + (size_t)b * Nc * Hc;
    float4 acc[8];
#pragma unroll
    for (int i = 0; i < 8; ++i) acc[i] = make_float4(0.f, 0.f, 0.f, 0.f);
    for (int jq = 0; jq < 64; ++jq) {
        int j = jg * 64 + jq;
        float4 x = *(const float4*)(Xyb + (size_t)j * Hc + h4 * 4);
#pragma unroll
        for (int i = 0; i < 8; ++i) {
            float av = als[i * Nc + j];
            acc[i].x = fmaf(av, x.x, acc[i].x); acc[i].y = fmaf(av, x.y, acc[i].y);
            acc[i].z = fmaf(av, x.z, acc[i].z); acc[i].w = fmaf(av, x.w, acc[i].w);
        }
    }
#pragma unroll
    for (int i = 0; i < 8; ++i) part4[jg * 256 + i * 32 + h4] = acc[i];
    __syncthreads();
    {
        int i = t >> 5, hq = t & 31;   // output (row i, h = hq*4..+3)
        float4 s = part4[i * 32 + hq];
#pragma unroll
        for (int g = 1; g < 8; ++g) {
            float4 p = part4[g * 256 + i * 32 + hq];
            s.x += p.x; s.y += p.y; s.z += p.z; s.w += p.w;
        }
        // We·ctx epilogue
        const float* c = ctxs + i * 32;
        float wec[4];
#pragma unroll
        for (int ho_ = 0; ho_ < 4; ++ho_) {
            const float4* wrow = (const float4*)(we_w + (size_t)(hq * 4 + ho_) * 32);
            float sv = 0.f;
#pragma unroll
            for (int q = 0; q < 8; ++q) {
                float4 w4 = wrow[q];
                sv = fmaf(w4.x, c[4 * q], sv); sv = fmaf(w4.y, c[4 * q + 1], sv);
                sv = fmaf(w4.z, c[4 * q + 2], sv); sv = fmaf(w4.w, c[4 * q + 3], sv);
            }
            wec[ho_] = sv;
        }
        size_t o = ((size_t)b * Nc + i0 + i) * Hc + hq * 4;
        float4 wb = *(const float4*)(we_b + hq * 4);
        float4 g = *(const float4*)(GS + o);
        float4 outv;
        outv.x = s.x + wec[0] + wb.x + g.x;
        outv.y = s.y + wec[1] + wb.y + g.y;
        outv.z = s.z + wec[2] + wb.z + g.z;
        outv.w = s.w + wec[3] + wb.w + g.w;
        *(float4*)(Xbar + o) = outv;
    }
}

// Fused SE: y2[b,:] = sigmoid(lin2(relu(lin1(sum_i Xbar[b,i,:]))))  grid B, 256 thr
__global__ __launch_bounds__(256) void se_fused(
        const float* __restrict__ Xbar, const float* __restrict__ l1w,
        const float* __restrict__ l1b, const float* __restrict__ l2w,
        const float* __restrict__ l2b, float* __restrict__ y2) {
    int b = blockIdx.x;
    int t = threadIdx.x;
    __shared__ float s2[256];
    __shared__ float s[Hc];
    __shared__ float y1s[REDc];
    int h = t & 127, half = t >> 7;
    const float* Xb = Xbar + ((size_t)b * Nc + half * 256) * Hc;
    float acc = 0.f;
    for (int i = 0; i < 256; ++i) acc += Xb[(size_t)i * Hc + h];
    s2[t] = acc;
    __syncthreads();
    if (t < 128) s[t] = s2[t] + s2[t + 128];
    __syncthreads();
    if (t < REDc) {
        float a = l1b[t];
        const float* w = l1w + (size_t)t * Hc;
        for (int k = 0; k < Hc; ++k) a = fmaf(s[k], w[k], a);
        y1s[t] = fmaxf(a, 0.f);
    }
    __syncthreads();
    if (t < 128) {
        float a = l2b[t];
        const float* w2 = l2w + (size_t)t * REDc;
#pragma unroll
        for (int k = 0; k < REDc; ++k) a = fmaf(y1s[k], w2[k], a);
        y2[(size_t)b * Hc + t] = 1.f / (1.f + __expf(-a));
    }
}

// head: grid B*N, 64 threads
__global__ __launch_bounds__(64) void head_kernel(const float* __restrict__ Xp, const float* __restrict__ h1w,
                            const float* __restrict__ h1b, const float* __restrict__ h2w,
                            const float* __restrict__ h2b, float* __restrict__ out) {
    int m = blockIdx.x;
    int t = threadIdx.x;
    __shared__ float xs[Hc];
    __shared__ float hs[64];
    xs[t] = Xp[(size_t)m * Hc + t];
    xs[t + 64] = Xp[(size_t)m * Hc + t + 64];
    __syncthreads();
    float a = h1b[t];
    const float* w = h1w + (size_t)t * Hc;
    for (int k = 0; k < Hc; ++k) a = fmaf(xs[k], w[k], a);
    hs[t] = fmaxf(a, 0.f);
    __syncthreads();
    if (t < OUTc) {
        float o = h2b[t];
        const float* w2 = h2w + (size_t)t * 64;
#pragma unroll
        for (int k = 0; k < 64; ++k) o = fmaf(hs[k], w2[k], o);
        out[(size_t)m * OUTc + t] = o;
    }
}

extern "C" void kernel_launch(void* const* d_in, const int* in_sizes, int n_in,
                              void* d_out, int out_size, void* d_ws, size_t ws_size,
                              hipStream_t stream) {
    const float* X       = (const float*)d_in[0];
    const float* A       = (const float*)d_in[1];
    const float* Acg     = (const float*)d_in[2];
    const float* embed_w = (const float*)d_in[3];
    const float* embed_b = (const float*)d_in[4];
    const float* topo_eps= (const float*)d_in[5];
    const float* topo_w  = (const float*)d_in[6];
    const float* topo_b  = (const float*)d_in[7];
    const float* theta   = (const float*)d_in[8];
    const float* gin_eps = (const float*)d_in[9];
    const float* gin_w   = (const float*)d_in[10];
    const float* gin_b   = (const float*)d_in[11];
    const float* wo      = (const float*)d_in[12];
    const float* w1      = (const float*)d_in[13];
    const float* wphi    = (const float*)d_in[14];
    const float* wy_w    = (const float*)d_in[15];
    const float* wy_b    = (const float*)d_in[16];
    const float* we_w    = (const float*)d_in[17];
    const float* we_b    = (const float*)d_in[18];
    const float* lin1_w  = (const float*)d_in[19];
    const float* lin1_b  = (const float*)d_in[20];
    const float* lin2_w  = (const float*)d_in[21];
    const float* lin2_b  = (const float*)d_in[22];
    const float* mlp_w   = (const float*)d_in[23];
    const float* mlp_b   = (const float*)d_in[24];
    const float* head1_w = (const float*)d_in[25];
    const float* head1_b = (const float*)d_in[26];
    const float* head2_w = (const float*)d_in[27];
    const float* head2_b = (const float*)d_in[28];
    float* out = (float*)d_out;

    float* ws = (float*)d_ws;
    const int MN = Bc * Nc;              // 4096
    const size_t SZ = (size_t)MN * Hc;   // 524288
    float* Xh   = ws;
    float* Xp   = Xh + SZ;
    float* T1   = Xp + SZ;
    float* T2   = T1 + SZ;
    float* GS   = T2 + SZ;
    float* Xy   = GS + SZ;
    float* S    = Xy + SZ;                       // B*N*N alpha
    float* hov  = S + (size_t)Bc * Nc * Nc;
    float* h1v  = hov + (size_t)MN * Atc;
    float* ctxv = h1v + (size_t)MN * Atc;
    float* y2   = ctxv + (size_t)MN * Atc;
    float* Xbar = T1;                            // alias: T1 dead after gin gemm

    gemm256<8, INc, 0><<<MN / 8, 256, 0, stream>>>(X, embed_w, embed_b, Xh, nullptr);
    spmm2<<<MN, 128, 0, stream>>>(A, Acg, Xh, topo_eps, topo_eps, T1, T2);
    gemm2_topo<<<MN / 8, 256, 0, stream>>>(T1, T2, topo_w, topo_b, Xh, theta, Xp);

    for (int l = 0; l < Lc; ++l) {
        spmm2<<<MN, 128, 0, stream>>>(A, Acg, Xp, gin_eps + l * 2, gin_eps + l * 2 + 1, T1, T2);
        gemm2_gin<<<MN / 8, 256, 0, stream>>>(T1, T2,
            gin_w + (size_t)(l * 2 + 0) * Hc * Hc, gin_b + (size_t)(l * 2 + 0) * Hc,
            gin_w + (size_t)(l * 2 + 1) * Hc * Hc, gin_b + (size_t)(l * 2 + 1) * Hc, GS);
        qkv_gemm<<<MN / 8, 256, 0, stream>>>(Xp, wy_w + (size_t)l * Hc * Hc, wy_b + (size_t)l * Hc,
            wo + (size_t)l * Atc * Hc, w1 + (size_t)l * Atc * Hc, Xy, hov, h1v);
        score_sm<<<MN / 8, 256, 0, stream>>>(hov, h1v, wphi + (size_t)l * Atc, S);
        ctx_kernel<<<MN, 256, 0, stream>>>(S, hov, h1v, ctxv);
        attn_out2<<<MN / 8, 256, 0, stream>>>(S, Xy, ctxv, we_w + (size_t)l * Hc * Atc,
                                              we_b + (size_t)l * Hc, GS, Xbar);
        se_fused<<<Bc, 256, 0, stream>>>(Xbar, lin1_w + (size_t)l * REDc * Hc, lin1_b + (size_t)l * REDc,
                                         lin2_w + (size_t)l * Hc * REDc, lin2_b + (size_t)l * Hc, y2);
        gemm256<8, Hc, 0><<<MN / 8, 256, 0, stream>>>(Xbar, mlp_w + (size_t)l * Hc * Hc,
                                                      mlp_b + (size_t)l * Hc, Xp, y2);
    }
    head_kernel<<<MN, 64, 0, stream>>>(Xp, head1_w, head1_b, head2_w, head2_b, out);
}